// Round 3
// baseline (2805.812 us; speedup 1.0000x reference)
//
#include <hip/hip_runtime.h>

// GRU seq2seq, MI355X gfx950. Round 3: register-resident GRU combine.
//   64 blocks x 512 threads (8 waves); each block owns 32 batch rows (2 MFMA
//   M-tiles) for all 504 steps. Wave w owns columns [w*16, w*16+16) and
//   computes gates r/z/n (n-tiles w, w+8, w+16) for BOTH the input and hidden
//   gemms of both M-tiles -> GRU combine entirely in registers off the MFMA
//   accumulators. h lives in lane registers; bf16 A-frag copy in LDS,
//   double-buffered by step parity => 2 barriers per encoder step, no gate
//   LDS buffers at all. Weights pre-swizzled bf16 B-frags in d_ws (prep).

typedef unsigned short ushort_t;
typedef unsigned int uint_t;
typedef __attribute__((ext_vector_type(8))) short short8;
typedef __attribute__((ext_vector_type(4))) float f32x4;

#define BT   32     // batch rows per block
#define NT   512    // 8 waves
#define HD   128
#define G3   384
#define TIN  336
#define TOUT 168
#define NFE  16
#define NB   64     // 2048 / BT
#define HS   68     // padded float stride of fc1 output

// d_ws offsets in short8 (16B) units
#define OFF_EWHH0 0
#define OFF_EWIH1 6144
#define OFF_EWHH1 12288
#define OFF_DWHH0 18432
#define OFF_DWIH1 24576
#define OFF_DWHH1 30720
#define OFF_EWIH0 36864
#define OFF_FW1   38400

__device__ __forceinline__ ushort_t f2bf(float f) {
    union { float f; uint_t u; } v; v.f = f;
    uint_t r = v.u + 0x7FFFu + ((v.u >> 16) & 1u);
    return (ushort_t)(r >> 16);
}
__device__ __forceinline__ float sigm(float x) {
    return 1.0f / (1.0f + __expf(-x));
}
__device__ __forceinline__ float tanh_fast(float x) {
    return 2.0f / (1.0f + __expf(-2.0f * x)) - 1.0f;
}

// ---------------- prep: fp32 weights -> bf16 MFMA B-fragments ----------------
extern "C" __global__ __launch_bounds__(64)
void prep_kernel(const float* __restrict__ eWhh0, const float* __restrict__ eWih1,
                 const float* __restrict__ eWhh1, const float* __restrict__ dWhh0,
                 const float* __restrict__ dWih1, const float* __restrict__ dWhh1,
                 const float* __restrict__ eWih0, const float* __restrict__ fW1,
                 uint4* __restrict__ ws)
{
    const int g = blockIdx.x;           // frag id in [0, 616)
    const int L = threadIdx.x;
    const int n_lo = L & 15, q = L >> 4;

    const float* src; int n, kb, Ksrc, dst16;
    if (g < 576) {
        const int m = g / 96, lf = g % 96;
        const float* hs[6] = {eWhh0, eWih1, eWhh1, dWhh0, dWih1, dWhh1};
        src = hs[m];
        const int nt = lf >> 2, kf = lf & 3;
        n = nt * 16 + n_lo; kb = kf * 32 + q * 8; Ksrc = 128;
        dst16 = m * 6144 + lf * 64 + L;
    } else if (g < 600) {
        const int nt = g - 576;
        src = eWih0; n = nt * 16 + n_lo; kb = q * 8; Ksrc = 16;
        dst16 = OFF_EWIH0 + nt * 64 + L;
    } else {
        const int lf = g - 600;
        src = fW1; n = (lf >> 2) * 16 + n_lo; kb = (lf & 3) * 32 + q * 8; Ksrc = 128;
        dst16 = OFF_FW1 + lf * 64 + L;
    }

    ushort_t h[8];
    #pragma unroll
    for (int j = 0; j < 8; ++j) {
        const int k = kb + j;
        h[j] = (k < Ksrc) ? f2bf(src[n * Ksrc + k]) : (ushort_t)0;
    }
    uint4 o;
    o.x = (uint_t)h[0] | ((uint_t)h[1] << 16);
    o.y = (uint_t)h[2] | ((uint_t)h[3] << 16);
    o.z = (uint_t)h[4] | ((uint_t)h[5] << 16);
    o.w = (uint_t)h[6] | ((uint_t)h[7] << 16);
    ws[dst16] = o;
}

// dual gemm: gates for input path (KFI kf) and hidden path (4 kf), 3 n-tiles
// (r/z/n), 2 m-tiles. Accumulators ai/ah indexed [gate][mt].
template<int KFI>
__device__ __forceinline__ void dual_gemm(const short8* __restrict__ Wi,
                                          const short8* __restrict__ Wh,
                                          const short8 (&Ai)[2][KFI],
                                          const short8 (&Ah)[2][4],
                                          int wv, int L,
                                          f32x4 (&ai)[3][2], f32x4 (&ah)[3][2])
{
    #pragma unroll
    for (int t3 = 0; t3 < 3; ++t3) {
        const int nt = wv + t3 * 8;
        #pragma unroll
        for (int kf = 0; kf < 4; ++kf) {
            const short8 bh = Wh[(nt * 4 + kf) * 64 + L];
            #pragma unroll
            for (int mt = 0; mt < 2; ++mt)
                ah[t3][mt] = __builtin_amdgcn_mfma_f32_16x16x32_bf16(
                    Ah[mt][kf], bh, ah[t3][mt], 0, 0, 0);
        }
        #pragma unroll
        for (int kf = 0; kf < KFI; ++kf) {
            const short8 bi = Wi[(nt * KFI + kf) * 64 + L];
            #pragma unroll
            for (int mt = 0; mt < 2; ++mt)
                ai[t3][mt] = __builtin_amdgcn_mfma_f32_16x16x32_bf16(
                    Ai[mt][kf], bi, ai[t3][mt], 0, 0, 0);
        }
    }
}

// combine 4 rows of one m-tile in registers; update h regs; scatter bf16 to
// A-frag LDS at wb (stride 8 shorts per row).
__device__ __forceinline__ void combine_store(const f32x4& air, const f32x4& aiz,
                                              const f32x4& ain, const f32x4& ahr,
                                              const f32x4& ahz, const f32x4& ahn,
                                              float brz, float bzz, float bin,
                                              float bhn, float* hreg,
                                              ushort_t* wb)
{
    #pragma unroll
    for (int r_ = 0; r_ < 4; ++r_) {
        const float rg = sigm(air[r_] + ahr[r_] + brz);
        const float zg = sigm(aiz[r_] + ahz[r_] + bzz);
        const float ng = tanh_fast(ain[r_] + bin + rg * (ahn[r_] + bhn));
        const float hn = (1.f - zg) * ng + zg * hreg[r_];
        hreg[r_] = hn;
        wb[r_ * 8] = f2bf(hn);
    }
}

extern "C" __global__ __launch_bounds__(NT)
void gru_seq2seq_kernel(
    const float* __restrict__ x,
    const float* __restrict__ ebih0, const float* __restrict__ ebhh0,
    const float* __restrict__ ebih1, const float* __restrict__ ebhh1,
    const float* __restrict__ dWih0, const float* __restrict__ dbih0,
    const float* __restrict__ dbhh0,
    const float* __restrict__ dbih1, const float* __restrict__ dbhh1,
    const float* __restrict__ fb1, const float* __restrict__ fW2,
    const float* __restrict__ fb2,
    const short8* __restrict__ wf,
    float* __restrict__ out)
{
    // A-fragment stores, double-buffered by step parity: [par][mt][kf][512]
    __shared__ ushort_t h0f[2][2][4][512];
    __shared__ ushort_t h1f[2][2][4][512];
    __shared__ ushort_t xf[2][2][512];      // [par][mt][512], kf=0 only
    __shared__ float hid[BT * HS];
    __shared__ float inp[BT];
    __shared__ float fw2l[64];

    const int t = threadIdx.x;
    const int L = t & 63, w = t >> 6;       // w = column-tile owner
    const int col16 = L & 15, q = L >> 4;
    const int col = w * 16 + col16;         // owned column in [0,128)
    const int b0 = blockIdx.x * BT;

    for (int i = t; i < 8192; i += NT) {
        (&h0f[0][0][0][0])[i] = 0;
        (&h1f[0][0][0][0])[i] = 0;
    }
    for (int i = t; i < 2048; i += NT) (&xf[0][0][0])[i] = 0;
    if (t < 64) fw2l[t] = fW2[t];
    if (t < BT) inp[t] = 0.f;

    // per-lane bias preloads (folded: r/z gates take bih+bhh; n keeps split)
    const float e0_rz = ebih0[col] + ebhh0[col];
    const float e0_zz = ebih0[HD + col] + ebhh0[HD + col];
    const float e0_in = ebih0[2 * HD + col];
    const float e0_hn = ebhh0[2 * HD + col];
    const float e1_rz = ebih1[col] + ebhh1[col];
    const float e1_zz = ebih1[HD + col] + ebhh1[HD + col];
    const float e1_in = ebih1[2 * HD + col];
    const float e1_hn = ebhh1[2 * HD + col];
    const float d0_rz = dbih0[col] + dbhh0[col];
    const float d0_zz = dbih0[HD + col] + dbhh0[HD + col];
    const float d0_in = dbih0[2 * HD + col];
    const float d0_hn = dbhh0[2 * HD + col];
    const float d1_rz = dbih1[col] + dbhh1[col];
    const float d1_zz = dbih1[HD + col] + dbhh1[HD + col];
    const float d1_in = dbih1[2 * HD + col];
    const float d1_hn = dbhh1[2 * HD + col];
    const float w0r = dWih0[col], w0z = dWih0[HD + col], w0n = dWih0[2 * HD + col];
    const float fb1v = fb1[(w >> 1) * 16 + col16];

    float h0r[8] = {0, 0, 0, 0, 0, 0, 0, 0};   // [mt*4 + r_]
    float h1r[8] = {0, 0, 0, 0, 0, 0, 0, 0};

    // h-scatter offset for owned col (A-frag layout), within one [kf][512] blk:
    const int kfc = col >> 5, qq = (col >> 3) & 3, jc = col & 7;
    const int hwo = kfc * 512 + (qq * 16 + q * 4) * 8 + jc;  // + r_*8 per row

    // x loader mapping: thread t -> (row xr, feat xfeat)
    const int xr = t >> 4, xfeat = t & 15;
    const int xscat = (xr >> 4) * 512 + (((xfeat >> 3) * 16) + (xr & 15)) * 8 + (xfeat & 7);
    float xv = x[((b0 + xr) * TIN + 0) * NFE + xfeat];

    __syncthreads();
    // pre-scatter x(0) into xf[0]
    (&xf[0][0][0])[xscat] = f2bf(xv);
    if (TIN > 1) xv = x[((b0 + xr) * TIN + 1) * NFE + xfeat];
    __syncthreads();

    // ---------------- encoder ----------------
    for (int s = 0; s < TIN; ++s) {
        const int p = s & 1;
        // stage x(s+1) into the other buffer (read buffer is xf[p])
        if (s + 1 < TIN) {
            (&xf[0][0][0])[(1 - p) * 1024 + xscat] = f2bf(xv);
            if (s + 2 < TIN) xv = x[((b0 + xr) * TIN + s + 2) * NFE + xfeat];
        }

        // ----- layer 0 -----
        {
            short8 Ai[2][1], Ah[2][4];
            #pragma unroll
            for (int mt = 0; mt < 2; ++mt) {
                Ai[mt][0] = *(const short8*)&xf[p][mt][L * 8];
                #pragma unroll
                for (int kf = 0; kf < 4; ++kf)
                    Ah[mt][kf] = *(const short8*)&h0f[p][mt][kf][L * 8];
            }
            f32x4 ai[3][2], ah[3][2];
            #pragma unroll
            for (int t3 = 0; t3 < 3; ++t3)
                #pragma unroll
                for (int mt = 0; mt < 2; ++mt) {
                    ai[t3][mt] = (f32x4){0.f, 0.f, 0.f, 0.f};
                    ah[t3][mt] = (f32x4){0.f, 0.f, 0.f, 0.f};
                }
            dual_gemm<1>(wf + OFF_EWIH0, wf + OFF_EWHH0, Ai, Ah, w, L, ai, ah);
            #pragma unroll
            for (int mt = 0; mt < 2; ++mt)
                combine_store(ai[0][mt], ai[1][mt], ai[2][mt],
                              ah[0][mt], ah[1][mt], ah[2][mt],
                              e0_rz, e0_zz, e0_in, e0_hn, &h0r[mt * 4],
                              &(&h0f[0][0][0][0])[((1 - p) * 2 + mt) * 2048 + hwo]);
        }
        __syncthreads();

        // ----- layer 1 -----
        {
            short8 Ai[2][4], Ah[2][4];
            #pragma unroll
            for (int mt = 0; mt < 2; ++mt)
                #pragma unroll
                for (int kf = 0; kf < 4; ++kf) {
                    Ai[mt][kf] = *(const short8*)&h0f[1 - p][mt][kf][L * 8];
                    Ah[mt][kf] = *(const short8*)&h1f[p][mt][kf][L * 8];
                }
            f32x4 ai[3][2], ah[3][2];
            #pragma unroll
            for (int t3 = 0; t3 < 3; ++t3)
                #pragma unroll
                for (int mt = 0; mt < 2; ++mt) {
                    ai[t3][mt] = (f32x4){0.f, 0.f, 0.f, 0.f};
                    ah[t3][mt] = (f32x4){0.f, 0.f, 0.f, 0.f};
                }
            dual_gemm<4>(wf + OFF_EWIH1, wf + OFF_EWHH1, Ai, Ah, w, L, ai, ah);
            #pragma unroll
            for (int mt = 0; mt < 2; ++mt)
                combine_store(ai[0][mt], ai[1][mt], ai[2][mt],
                              ah[0][mt], ah[1][mt], ah[2][mt],
                              e1_rz, e1_zz, e1_in, e1_hn, &h1r[mt * 4],
                              &(&h1f[0][0][0][0])[((1 - p) * 2 + mt) * 2048 + hwo]);
        }
        __syncthreads();
    }

    // ---------------- decoder ----------------
    for (int s = 0; s < TOUT; ++s) {
        const int p = s & 1;

        // ----- layer 0: gi = outer(inp, dWih0), gh = MFMA -----
        {
            short8 Ah[2][4];
            #pragma unroll
            for (int mt = 0; mt < 2; ++mt)
                #pragma unroll
                for (int kf = 0; kf < 4; ++kf)
                    Ah[mt][kf] = *(const short8*)&h0f[p][mt][kf][L * 8];
            f32x4 ah[3][2];
            #pragma unroll
            for (int t3 = 0; t3 < 3; ++t3)
                #pragma unroll
                for (int mt = 0; mt < 2; ++mt)
                    ah[t3][mt] = (f32x4){0.f, 0.f, 0.f, 0.f};
            #pragma unroll
            for (int t3 = 0; t3 < 3; ++t3) {
                const int nt = w + t3 * 8;
                #pragma unroll
                for (int kf = 0; kf < 4; ++kf) {
                    const short8 bh = wf[OFF_DWHH0 + (nt * 4 + kf) * 64 + L];
                    #pragma unroll
                    for (int mt = 0; mt < 2; ++mt)
                        ah[t3][mt] = __builtin_amdgcn_mfma_f32_16x16x32_bf16(
                            Ah[mt][kf], bh, ah[t3][mt], 0, 0, 0);
                }
            }
            #pragma unroll
            for (int mt = 0; mt < 2; ++mt) {
                ushort_t* wb = &(&h0f[0][0][0][0])[((1 - p) * 2 + mt) * 2048 + hwo];
                #pragma unroll
                for (int r_ = 0; r_ < 4; ++r_) {
                    const float iv = inp[mt * 16 + q * 4 + r_];
                    const float rg = sigm(iv * w0r + ah[0][mt][r_] + d0_rz);
                    const float zg = sigm(iv * w0z + ah[1][mt][r_] + d0_zz);
                    const float ng = tanh_fast(iv * w0n + d0_in + rg * (ah[2][mt][r_] + d0_hn));
                    const float hn = (1.f - zg) * ng + zg * h0r[mt * 4 + r_];
                    h0r[mt * 4 + r_] = hn;
                    wb[r_ * 8] = f2bf(hn);
                }
            }
        }
        __syncthreads();

        // ----- layer 1 -----
        {
            short8 Ai[2][4], Ah[2][4];
            #pragma unroll
            for (int mt = 0; mt < 2; ++mt)
                #pragma unroll
                for (int kf = 0; kf < 4; ++kf) {
                    Ai[mt][kf] = *(const short8*)&h0f[1 - p][mt][kf][L * 8];
                    Ah[mt][kf] = *(const short8*)&h1f[p][mt][kf][L * 8];
                }
            f32x4 ai[3][2], ah[3][2];
            #pragma unroll
            for (int t3 = 0; t3 < 3; ++t3)
                #pragma unroll
                for (int mt = 0; mt < 2; ++mt) {
                    ai[t3][mt] = (f32x4){0.f, 0.f, 0.f, 0.f};
                    ah[t3][mt] = (f32x4){0.f, 0.f, 0.f, 0.f};
                }
            dual_gemm<4>(wf + OFF_DWIH1, wf + OFF_DWHH1, Ai, Ah, w, L, ai, ah);
            #pragma unroll
            for (int mt = 0; mt < 2; ++mt)
                combine_store(ai[0][mt], ai[1][mt], ai[2][mt],
                              ah[0][mt], ah[1][mt], ah[2][mt],
                              d1_rz, d1_zz, d1_in, d1_hn, &h1r[mt * 4],
                              &(&h1f[0][0][0][0])[((1 - p) * 2 + mt) * 2048 + hwo]);
        }
        __syncthreads();

        // ----- fc1: hid = relu(h1 @ fW1.T + fb1), 8 tile-gemms / 8 waves -----
        {
            const int mt = w & 1, nt = w >> 1;
            f32x4 acc = {0.f, 0.f, 0.f, 0.f};
            #pragma unroll
            for (int kf = 0; kf < 4; ++kf) {
                const short8 a = *(const short8*)&h1f[1 - p][mt][kf][L * 8];
                const short8 b = wf[OFF_FW1 + (nt * 4 + kf) * 64 + L];
                acc = __builtin_amdgcn_mfma_f32_16x16x32_bf16(a, b, acc, 0, 0, 0);
            }
            #pragma unroll
            for (int r_ = 0; r_ < 4; ++r_)
                hid[(mt * 16 + q * 4 + r_) * HS + nt * 16 + col16] =
                    fmaxf(acc[r_] + fb1v, 0.f);
        }
        __syncthreads();

        // ----- fc2 (wave 0): 2 lanes per row -----
        if (w == 0) {
            const int r = L >> 1, half = L & 1;
            const float* hp = &hid[r * HS + half * 32];
            const float* wp = &fw2l[half * 32];
            float s_ = 0.f;
            #pragma unroll
            for (int k4 = 0; k4 < 8; ++k4) {
                const float4 hv = *(const float4*)(hp + k4 * 4);
                const float4 wv = *(const float4*)(wp + k4 * 4);
                s_ = fmaf(hv.x, wv.x, s_);
                s_ = fmaf(hv.y, wv.y, s_);
                s_ = fmaf(hv.z, wv.z, s_);
                s_ = fmaf(hv.w, wv.w, s_);
            }
            s_ += __shfl_xor(s_, 1, 64);
            if (half == 0) {
                const float v = fmaxf(s_ + fb2[0], 0.f);
                inp[r] = v;
                out[(b0 + r) * TOUT + s] = v;
            }
        }
        __syncthreads();
    }
}

extern "C" void kernel_launch(void* const* d_in, const int* in_sizes, int n_in,
                              void* d_out, int out_size, void* d_ws, size_t ws_size,
                              hipStream_t stream) {
    const float* x     = (const float*)d_in[0];
    const float* eWih0 = (const float*)d_in[1];
    const float* eWhh0 = (const float*)d_in[2];
    const float* ebih0 = (const float*)d_in[3];
    const float* ebhh0 = (const float*)d_in[4];
    const float* eWih1 = (const float*)d_in[5];
    const float* eWhh1 = (const float*)d_in[6];
    const float* ebih1 = (const float*)d_in[7];
    const float* ebhh1 = (const float*)d_in[8];
    const float* dWih0 = (const float*)d_in[9];
    const float* dWhh0 = (const float*)d_in[10];
    const float* dbih0 = (const float*)d_in[11];
    const float* dbhh0 = (const float*)d_in[12];
    const float* dWih1 = (const float*)d_in[13];
    const float* dWhh1 = (const float*)d_in[14];
    const float* dbih1 = (const float*)d_in[15];
    const float* dbhh1 = (const float*)d_in[16];
    const float* fW1   = (const float*)d_in[17];
    const float* fb1   = (const float*)d_in[18];
    const float* fW2   = (const float*)d_in[19];
    const float* fb2   = (const float*)d_in[20];
    float* out = (float*)d_out;

    hipLaunchKernelGGL(prep_kernel, dim3(616), dim3(64), 0, stream,
                       eWhh0, eWih1, eWhh1, dWhh0, dWih1, dWhh1, eWih0, fW1,
                       (uint4*)d_ws);
    hipLaunchKernelGGL(gru_seq2seq_kernel, dim3(NB), dim3(NT), 0, stream,
                       x, ebih0, ebhh0, ebih1, ebhh1,
                       dWih0, dbih0, dbhh0, dbih1, dbhh1,
                       fb1, fW2, fb2,
                       (const short8*)d_ws, out);
}

// Round 4
// 1320.343 us; speedup vs baseline: 2.1251x; 2.1251x over previous
//
#include <hip/hip_runtime.h>

// GRU seq2seq, MI355X gfx950. Round 4: register-resident WEIGHTS.
//   128 blocks x 512 threads (8 waves, 2/SIMD); each block owns 16 batch rows.
//   Wave w owns gate columns [w*16,w*16+16) = n-tiles {w, w+8, w+16} and holds
//   ALL its weight B-fragments in VGPRs (39-40 frags ~ 160 VGPR), loaded once
//   per phase -> ZERO global loads inside the 504-step recurrence. GRU combine
//   in registers off MFMA accumulators (C-layout row=q*4+r, col=lane&15).
//   h state in lane registers; bf16 A-frag copy in LDS double-buffered by step
//   parity => 2 barriers/encoder step. Weights pre-swizzled by prep kernel.

typedef unsigned short ushort_t;
typedef unsigned int uint_t;
typedef __attribute__((ext_vector_type(8))) short short8;
typedef __attribute__((ext_vector_type(4))) float f32x4;

#define BT   16     // batch rows per block (one MFMA M-tile)
#define NT   512    // 8 waves
#define HD   128
#define TIN  336
#define TOUT 168
#define NFE  16
#define NB   128    // 2048 / BT
#define HS   68     // padded float stride of fc1 output

// d_ws offsets in short8 (16B) units
#define OFF_EWHH0 0
#define OFF_EWIH1 6144
#define OFF_EWHH1 12288
#define OFF_DWHH0 18432
#define OFF_DWIH1 24576
#define OFF_DWHH1 30720
#define OFF_EWIH0 36864
#define OFF_FW1   38400

__device__ __forceinline__ ushort_t f2bf(float f) {
    union { float f; uint_t u; } v; v.f = f;
    uint_t r = v.u + 0x7FFFu + ((v.u >> 16) & 1u);
    return (ushort_t)(r >> 16);
}
__device__ __forceinline__ float sigm(float x) {
    return 1.0f / (1.0f + __expf(-x));
}
__device__ __forceinline__ float tanh_fast(float x) {
    return 2.0f / (1.0f + __expf(-2.0f * x)) - 1.0f;
}

// ---------------- prep: fp32 weights -> bf16 MFMA B-fragments ----------------
extern "C" __global__ __launch_bounds__(64)
void prep_kernel(const float* __restrict__ eWhh0, const float* __restrict__ eWih1,
                 const float* __restrict__ eWhh1, const float* __restrict__ dWhh0,
                 const float* __restrict__ dWih1, const float* __restrict__ dWhh1,
                 const float* __restrict__ eWih0, const float* __restrict__ fW1,
                 uint4* __restrict__ ws)
{
    const int g = blockIdx.x;           // frag id in [0, 616)
    const int L = threadIdx.x;
    const int n_lo = L & 15, q = L >> 4;

    const float* src; int n, kb, Ksrc, dst16;
    if (g < 576) {
        const int m = g / 96, lf = g % 96;
        const float* hs[6] = {eWhh0, eWih1, eWhh1, dWhh0, dWih1, dWhh1};
        src = hs[m];
        const int nt = lf >> 2, kf = lf & 3;
        n = nt * 16 + n_lo; kb = kf * 32 + q * 8; Ksrc = 128;
        dst16 = m * 6144 + lf * 64 + L;
    } else if (g < 600) {
        const int nt = g - 576;
        src = eWih0; n = nt * 16 + n_lo; kb = q * 8; Ksrc = 16;
        dst16 = OFF_EWIH0 + nt * 64 + L;
    } else {
        const int lf = g - 600;
        src = fW1; n = (lf >> 2) * 16 + n_lo; kb = (lf & 3) * 32 + q * 8; Ksrc = 128;
        dst16 = OFF_FW1 + lf * 64 + L;
    }

    ushort_t h[8];
    #pragma unroll
    for (int j = 0; j < 8; ++j) {
        const int k = kb + j;
        h[j] = (k < Ksrc) ? f2bf(src[n * Ksrc + k]) : (ushort_t)0;
    }
    uint4 o;
    o.x = (uint_t)h[0] | ((uint_t)h[1] << 16);
    o.y = (uint_t)h[2] | ((uint_t)h[3] << 16);
    o.z = (uint_t)h[4] | ((uint_t)h[5] << 16);
    o.w = (uint_t)h[6] | ((uint_t)h[7] << 16);
    ws[dst16] = o;
}

// combine 4 rows in registers; update h regs; scatter bf16 to A-frag LDS.
__device__ __forceinline__ void combine16(const f32x4& air, const f32x4& aiz,
                                          const f32x4& ain, const f32x4& ahr,
                                          const f32x4& ahz, const f32x4& ahn,
                                          float brz, float bzz, float bin,
                                          float bhn, float* hreg,
                                          ushort_t* wb)
{
    #pragma unroll
    for (int r_ = 0; r_ < 4; ++r_) {
        const float rg = sigm(air[r_] + ahr[r_] + brz);
        const float zg = sigm(aiz[r_] + ahz[r_] + bzz);
        const float ng = tanh_fast(ain[r_] + bin + rg * (ahn[r_] + bhn));
        const float hn = (1.f - zg) * ng + zg * hreg[r_];
        hreg[r_] = hn;
        wb[r_ * 8] = f2bf(hn);
    }
}

extern "C" __global__ __launch_bounds__(NT, 2)
void gru_seq2seq_kernel(
    const float* __restrict__ x,
    const float* __restrict__ ebih0, const float* __restrict__ ebhh0,
    const float* __restrict__ ebih1, const float* __restrict__ ebhh1,
    const float* __restrict__ dWih0, const float* __restrict__ dbih0,
    const float* __restrict__ dbhh0,
    const float* __restrict__ dbih1, const float* __restrict__ dbhh1,
    const float* __restrict__ fb1, const float* __restrict__ fW2,
    const float* __restrict__ fb2,
    const short8* __restrict__ wf,
    float* __restrict__ out)
{
    __shared__ ushort_t h0f[2][4][512];   // [parity][kf][lane*8+j]
    __shared__ ushort_t h1f[2][4][512];
    __shared__ ushort_t xf[2][512];
    __shared__ float hid[BT * HS];
    __shared__ float inp[BT];
    __shared__ float fw2l[64];

    const int t = threadIdx.x;
    const int L = t & 63, w = t >> 6;
    const int col16 = L & 15, q = L >> 4;
    const int col = w * 16 + col16;       // owned gate column in [0,128)
    const int b0 = blockIdx.x * BT;

    for (int i = t; i < 4096; i += NT) {
        (&h0f[0][0][0])[i] = 0;
        (&h1f[0][0][0])[i] = 0;
    }
    for (int i = t; i < 1024; i += NT) (&xf[0][0])[i] = 0;
    if (t < 64) fw2l[t] = fW2[t];
    if (t < BT) inp[t] = 0.f;

    // h-scatter offset for owned col (A-frag layout) within one parity block
    const int kfc = col >> 5, qq = (col >> 3) & 3, jc = col & 7;
    const int hwo = kfc * 512 + (qq * 16 + q * 4) * 8 + jc;  // + r_*8 per row

    // x loader mapping (first 256 threads, 1 elem each)
    const int xr = t >> 4, xfeat = t & 15;
    const int xscat = (((xfeat >> 3) * 16) + (xr & 15)) * 8 + (xfeat & 7);
    float xv = (t < 256) ? x[((b0 + xr) * TIN + 0) * NFE + xfeat] : 0.f;

    // encoder biases (per-lane, folded)
    const float e0_rz = ebih0[col] + ebhh0[col];
    const float e0_zz = ebih0[HD + col] + ebhh0[HD + col];
    const float e0_in = ebih0[2 * HD + col];
    const float e0_hn = ebhh0[2 * HD + col];
    const float e1_rz = ebih1[col] + ebhh1[col];
    const float e1_zz = ebih1[HD + col] + ebhh1[HD + col];
    const float e1_in = ebih1[2 * HD + col];
    const float e1_hn = ebhh1[2 * HD + col];

    float h0r[4] = {0, 0, 0, 0};
    float h1r[4] = {0, 0, 0, 0};

    // ---- encoder weight fragments -> registers (reused for decoder later) ----
    short8 Wa[3][4], Wb[3][4], Wc[3][4];   // eWhh0 / eWih1 / eWhh1
    short8 We[3];                          // eWih0 (K=32, zero-padded)
    #pragma unroll
    for (int t3 = 0; t3 < 3; ++t3) {
        const int nt = w + t3 * 8;
        We[t3] = wf[OFF_EWIH0 + nt * 64 + L];
        #pragma unroll
        for (int kf = 0; kf < 4; ++kf) {
            Wa[t3][kf] = wf[OFF_EWHH0 + (nt * 4 + kf) * 64 + L];
            Wb[t3][kf] = wf[OFF_EWIH1 + (nt * 4 + kf) * 64 + L];
            Wc[t3][kf] = wf[OFF_EWHH1 + (nt * 4 + kf) * 64 + L];
        }
    }

    __syncthreads();
    if (t < 256) {
        (&xf[0][0])[xscat] = f2bf(xv);
        xv = x[((b0 + xr) * TIN + 1) * NFE + xfeat];
    }
    __syncthreads();

    // ---------------- encoder ----------------
    for (int s = 0; s < TIN; ++s) {
        const int p = s & 1;
        if (s + 1 < TIN && t < 256) {
            (&xf[0][0])[(1 - p) * 512 + xscat] = f2bf(xv);
            if (s + 2 < TIN) xv = x[((b0 + xr) * TIN + s + 2) * NFE + xfeat];
        }

        // ----- layer 0 -----
        {
            const short8 Ax = *(const short8*)&xf[p][L * 8];
            short8 Ah[4];
            #pragma unroll
            for (int kf = 0; kf < 4; ++kf)
                Ah[kf] = *(const short8*)&h0f[p][kf][L * 8];
            f32x4 gi[3], gh[3];
            #pragma unroll
            for (int t3 = 0; t3 < 3; ++t3) {
                gi[t3] = (f32x4){0.f, 0.f, 0.f, 0.f};
                gh[t3] = (f32x4){0.f, 0.f, 0.f, 0.f};
            }
            #pragma unroll
            for (int t3 = 0; t3 < 3; ++t3) {
                #pragma unroll
                for (int kf = 0; kf < 4; ++kf)
                    gh[t3] = __builtin_amdgcn_mfma_f32_16x16x32_bf16(
                        Ah[kf], Wa[t3][kf], gh[t3], 0, 0, 0);
                gi[t3] = __builtin_amdgcn_mfma_f32_16x16x32_bf16(
                    Ax, We[t3], gi[t3], 0, 0, 0);
            }
            combine16(gi[0], gi[1], gi[2], gh[0], gh[1], gh[2],
                      e0_rz, e0_zz, e0_in, e0_hn, h0r,
                      &(&h0f[0][0][0])[(1 - p) * 2048 + hwo]);
        }
        __syncthreads();

        // ----- layer 1 -----
        {
            short8 Ai[4], Ah[4];
            #pragma unroll
            for (int kf = 0; kf < 4; ++kf) {
                Ai[kf] = *(const short8*)&h0f[1 - p][kf][L * 8];
                Ah[kf] = *(const short8*)&h1f[p][kf][L * 8];
            }
            f32x4 gi[3], gh[3];
            #pragma unroll
            for (int t3 = 0; t3 < 3; ++t3) {
                gi[t3] = (f32x4){0.f, 0.f, 0.f, 0.f};
                gh[t3] = (f32x4){0.f, 0.f, 0.f, 0.f};
            }
            #pragma unroll
            for (int t3 = 0; t3 < 3; ++t3) {
                #pragma unroll
                for (int kf = 0; kf < 4; ++kf) {
                    gi[t3] = __builtin_amdgcn_mfma_f32_16x16x32_bf16(
                        Ai[kf], Wb[t3][kf], gi[t3], 0, 0, 0);
                    gh[t3] = __builtin_amdgcn_mfma_f32_16x16x32_bf16(
                        Ah[kf], Wc[t3][kf], gh[t3], 0, 0, 0);
                }
            }
            combine16(gi[0], gi[1], gi[2], gh[0], gh[1], gh[2],
                      e1_rz, e1_zz, e1_in, e1_hn, h1r,
                      &(&h1f[0][0][0])[(1 - p) * 2048 + hwo]);
        }
        __syncthreads();
    }

    // keep decoder weight loads from being hoisted above the encoder loop
    asm volatile("" ::: "memory");

    // ---- decoder weights overwrite the SAME register arrays ----
    short8 Wd[4];                          // fW1 (waves 0-3 use it)
    #pragma unroll
    for (int t3 = 0; t3 < 3; ++t3) {
        const int nt = w + t3 * 8;
        #pragma unroll
        for (int kf = 0; kf < 4; ++kf) {
            Wa[t3][kf] = wf[OFF_DWHH0 + (nt * 4 + kf) * 64 + L];
            Wb[t3][kf] = wf[OFF_DWIH1 + (nt * 4 + kf) * 64 + L];
            Wc[t3][kf] = wf[OFF_DWHH1 + (nt * 4 + kf) * 64 + L];
        }
    }
    #pragma unroll
    for (int kf = 0; kf < 4; ++kf)
        Wd[kf] = wf[OFF_FW1 + ((w & 3) * 4 + kf) * 64 + L];

    // decoder per-lane constants
    const float d0_rz = dbih0[col] + dbhh0[col];
    const float d0_zz = dbih0[HD + col] + dbhh0[HD + col];
    const float d0_in = dbih0[2 * HD + col];
    const float d0_hn = dbhh0[2 * HD + col];
    const float d1_rz = dbih1[col] + dbhh1[col];
    const float d1_zz = dbih1[HD + col] + dbhh1[HD + col];
    const float d1_in = dbih1[2 * HD + col];
    const float d1_hn = dbhh1[2 * HD + col];
    const float w0r = dWih0[col], w0z = dWih0[HD + col], w0n = dWih0[2 * HD + col];
    const float fb1v = fb1[(w & 3) * 16 + col16];
    const float fb2v = fb2[0];

    // ---------------- decoder ----------------
    for (int s = 0; s < TOUT; ++s) {
        const int p = s & 1;

        // ----- layer 0: input gates = outer(inp, dWih0) -----
        {
            short8 Ah[4];
            #pragma unroll
            for (int kf = 0; kf < 4; ++kf)
                Ah[kf] = *(const short8*)&h0f[p][kf][L * 8];
            f32x4 gh[3];
            #pragma unroll
            for (int t3 = 0; t3 < 3; ++t3) gh[t3] = (f32x4){0.f, 0.f, 0.f, 0.f};
            #pragma unroll
            for (int t3 = 0; t3 < 3; ++t3)
                #pragma unroll
                for (int kf = 0; kf < 4; ++kf)
                    gh[t3] = __builtin_amdgcn_mfma_f32_16x16x32_bf16(
                        Ah[kf], Wa[t3][kf], gh[t3], 0, 0, 0);
            ushort_t* wb = &(&h0f[0][0][0])[(1 - p) * 2048 + hwo];
            #pragma unroll
            for (int r_ = 0; r_ < 4; ++r_) {
                const float iv = inp[q * 4 + r_];
                const float rg = sigm(iv * w0r + gh[0][r_] + d0_rz);
                const float zg = sigm(iv * w0z + gh[1][r_] + d0_zz);
                const float ng = tanh_fast(iv * w0n + d0_in + rg * (gh[2][r_] + d0_hn));
                const float hn = (1.f - zg) * ng + zg * h0r[r_];
                h0r[r_] = hn;
                wb[r_ * 8] = f2bf(hn);
            }
        }
        __syncthreads();

        // ----- layer 1 -----
        {
            short8 Ai[4], Ah[4];
            #pragma unroll
            for (int kf = 0; kf < 4; ++kf) {
                Ai[kf] = *(const short8*)&h0f[1 - p][kf][L * 8];
                Ah[kf] = *(const short8*)&h1f[p][kf][L * 8];
            }
            f32x4 gi[3], gh[3];
            #pragma unroll
            for (int t3 = 0; t3 < 3; ++t3) {
                gi[t3] = (f32x4){0.f, 0.f, 0.f, 0.f};
                gh[t3] = (f32x4){0.f, 0.f, 0.f, 0.f};
            }
            #pragma unroll
            for (int t3 = 0; t3 < 3; ++t3)
                #pragma unroll
                for (int kf = 0; kf < 4; ++kf) {
                    gi[t3] = __builtin_amdgcn_mfma_f32_16x16x32_bf16(
                        Ai[kf], Wb[t3][kf], gi[t3], 0, 0, 0);
                    gh[t3] = __builtin_amdgcn_mfma_f32_16x16x32_bf16(
                        Ah[kf], Wc[t3][kf], gh[t3], 0, 0, 0);
                }
            combine16(gi[0], gi[1], gi[2], gh[0], gh[1], gh[2],
                      d1_rz, d1_zz, d1_in, d1_hn, h1r,
                      &(&h1f[0][0][0])[(1 - p) * 2048 + hwo]);
        }
        __syncthreads();

        // ----- fc1 (waves 0-3): hid = relu(h1 @ fW1.T + fb1) -----
        if (w < 4) {
            f32x4 acc = {0.f, 0.f, 0.f, 0.f};
            #pragma unroll
            for (int kf = 0; kf < 4; ++kf) {
                const short8 a = *(const short8*)&h1f[1 - p][kf][L * 8];
                acc = __builtin_amdgcn_mfma_f32_16x16x32_bf16(a, Wd[kf], acc, 0, 0, 0);
            }
            #pragma unroll
            for (int r_ = 0; r_ < 4; ++r_)
                hid[(q * 4 + r_) * HS + w * 16 + col16] = fmaxf(acc[r_] + fb1v, 0.f);
        }
        __syncthreads();

        // ----- fc2 (wave 0): 4 lanes per row -----
        if (w == 0) {
            const int r = L >> 2, quarter = L & 3;
            const float* hp = &hid[r * HS + quarter * 16];
            const float* wp = &fw2l[quarter * 16];
            float s_ = 0.f;
            #pragma unroll
            for (int k4 = 0; k4 < 4; ++k4) {
                const float4 hv = *(const float4*)(hp + k4 * 4);
                const float4 wv = *(const float4*)(wp + k4 * 4);
                s_ = fmaf(hv.x, wv.x, s_);
                s_ = fmaf(hv.y, wv.y, s_);
                s_ = fmaf(hv.z, wv.z, s_);
                s_ = fmaf(hv.w, wv.w, s_);
            }
            s_ += __shfl_xor(s_, 1, 64);
            s_ += __shfl_xor(s_, 2, 64);
            if (quarter == 0) {
                const float v = fmaxf(s_ + fb2v, 0.f);
                inp[r] = v;
                out[(b0 + r) * TOUT + s] = v;
            }
        }
        __syncthreads();
    }
}

extern "C" void kernel_launch(void* const* d_in, const int* in_sizes, int n_in,
                              void* d_out, int out_size, void* d_ws, size_t ws_size,
                              hipStream_t stream) {
    const float* x     = (const float*)d_in[0];
    const float* eWih0 = (const float*)d_in[1];
    const float* eWhh0 = (const float*)d_in[2];
    const float* ebih0 = (const float*)d_in[3];
    const float* ebhh0 = (const float*)d_in[4];
    const float* eWih1 = (const float*)d_in[5];
    const float* eWhh1 = (const float*)d_in[6];
    const float* ebih1 = (const float*)d_in[7];
    const float* ebhh1 = (const float*)d_in[8];
    const float* dWih0 = (const float*)d_in[9];
    const float* dWhh0 = (const float*)d_in[10];
    const float* dbih0 = (const float*)d_in[11];
    const float* dbhh0 = (const float*)d_in[12];
    const float* dWih1 = (const float*)d_in[13];
    const float* dWhh1 = (const float*)d_in[14];
    const float* dbih1 = (const float*)d_in[15];
    const float* dbhh1 = (const float*)d_in[16];
    const float* fW1   = (const float*)d_in[17];
    const float* fb1   = (const float*)d_in[18];
    const float* fW2   = (const float*)d_in[19];
    const float* fb2   = (const float*)d_in[20];
    float* out = (float*)d_out;

    hipLaunchKernelGGL(prep_kernel, dim3(616), dim3(64), 0, stream,
                       eWhh0, eWih1, eWhh1, dWhh0, dWih1, dWhh1, eWih0, fW1,
                       (uint4*)d_ws);
    hipLaunchKernelGGL(gru_seq2seq_kernel, dim3(NB), dim3(NT), 0, stream,
                       x, ebih0, ebhh0, ebih1, ebhh1,
                       dWih0, dbih0, dbhh0, dbih1, dbhh1,
                       fb1, fW2, fb2,
                       (const short8*)d_ws, out);
}